// Round 13
// baseline (227.227 us; speedup 1.0000x reference)
//
#include <hip/hip_runtime.h>
#include <hip/hip_bf16.h>
#include <hip/hip_cooperative_groups.h>

namespace cg = cooperative_groups;

// CrossModalContrastiveLoss: B=8, C=256, H=W=32 -> N=8192 vectors of dim 256.
// loss = -( P - 1024 * sum_i log(sum_j exp(S_ij)) ) / 8388608,
// S = normalize(rgb) @ normalize(x)^T / 0.1.
// P analytic via bilinearity (verified r7-r12): P = ln2 * sum_b <rgbsum_b, xsum_b>
// (rgb side carries k2 = 10*log2(e) folded in at fp8 quantization, so
// S_mfma = k2*sim and exp(10 sim) = exp2(S_mfma)).
//
// Round-13: ONE cooperative dispatch. Phase 1 = r12 norm tiles (roles 0..511,
// grid-strided). grid.sync(). Phase 2 = r9-VERBATIM fp8 gemm (53-us config:
// A-loads -> rowexp -> prefetch -> barrier; b64 LDS reads), tiles 0..1023
// grid-strided. Done-counter finalize. LDS phases overlaid in one 33 KB
// buffer -> 4 blocks/CU -> grid 1024 = full co-residency (validated by the
// cooperative launch).

#define HWsz 1024
#define Cdim 256
#define Nvec 8192
#define CHW  (Cdim * HWsz)

typedef __attribute__((ext_vector_type(4))) float f32x4;

__global__ __launch_bounds__(256, 4) void fused_kernel(
    const float* __restrict__ rgb, const float* __restrict__ x,
    unsigned char* __restrict__ rgbq, unsigned char* __restrict__ xq,
    float* __restrict__ bpart, float* __restrict__ sumexp,
    unsigned int* __restrict__ done, float* __restrict__ out) {
  __shared__ __align__(16) unsigned char smem[33024];

  const int t = threadIdx.x;

  // ================= phase 1: normalize + fp8 quantize =================
  {
    float (*ssp)[33] = reinterpret_cast<float(*)[33]>(smem);            // 4224 B
    unsigned char (*tile)[272] =
        reinterpret_cast<unsigned char(*)[272]>(smem + 4224);           // 8704 B
    const int part = t >> 3;  // channel chunk (8 channels)
    const int q = t & 7;      // vector quad (4 vectors)
    const float k2 = 14.4269504089f;  // (1/T)*log2(e), folded into rgb side

    for (int role = blockIdx.x; role < 512; role += gridDim.x) {
      const int isx = role >> 8;
      const int tix = role & 255;
      const float* src = isx ? x : rgb;
      unsigned char* dst = isx ? xq : rgbq;
      const int n0 = tix * 32;
      const int b = n0 >> 10;
      const int hw0 = n0 & 1023;
      const float* p =
          src + (size_t)b * CHW + (size_t)part * 8 * HWsz + hw0 + q * 4;

      if (isx == 0 && t < 32) sumexp[tix * 32 + t] = 0.f;
      if (role == 0 && t == 0) done[0] = 0u;

      float va[4][8];
      float ss4[4] = {0.f, 0.f, 0.f, 0.f};
#pragma unroll
      for (int j = 0; j < 8; ++j) {
        const float4 v4 =
            *reinterpret_cast<const float4*>(p + (size_t)j * HWsz);
        va[0][j] = v4.x; va[1][j] = v4.y; va[2][j] = v4.z; va[3][j] = v4.w;
        ss4[0] += v4.x * v4.x; ss4[1] += v4.y * v4.y;
        ss4[2] += v4.z * v4.z; ss4[3] += v4.w * v4.w;
      }
#pragma unroll
      for (int k = 0; k < 4; ++k) ssp[part][q * 4 + k] = ss4[k];
      __syncthreads();

      const float topf = isx ? 1.0f : k2;
#pragma unroll
      for (int k = 0; k < 4; ++k) {
        float tot = 0.f;
#pragma unroll
        for (int p2 = 0; p2 < 32; ++p2) tot += ssp[p2][q * 4 + k];
        const float inv = topf / fmaxf(sqrtf(tot), 1e-12f);
        int pk0 = 0, pk1 = 0;
        pk0 = __builtin_amdgcn_cvt_pk_fp8_f32(va[0][0] * inv, va[0][1] * inv, pk0, false);
        pk0 = __builtin_amdgcn_cvt_pk_fp8_f32(va[0][2] * inv, va[0][3] * inv, pk0, true);
        pk1 = __builtin_amdgcn_cvt_pk_fp8_f32(va[0][4] * inv, va[0][5] * inv, pk1, false);
        pk1 = __builtin_amdgcn_cvt_pk_fp8_f32(va[0][6] * inv, va[0][7] * inv, pk1, true);
#pragma unroll
        for (int kk = 0; kk < 3; ++kk)
#pragma unroll
          for (int j = 0; j < 8; ++j) va[kk][j] = va[kk + 1][j];
        unsigned int* wp =
            reinterpret_cast<unsigned int*>(&tile[q * 4 + k][part * 8]);
        wp[0] = (unsigned int)pk0;
        wp[1] = (unsigned int)pk1;
      }
      __syncthreads();

      // coalesced store: 2 passes x (16 rows x 256 B), natural (N,C) layout
#pragma unroll
      for (int pass = 0; pass < 2; ++pass) {
        const int r = pass * 16 + (t >> 4);
        const int u = t & 15;
        *reinterpret_cast<uint4*>(dst + (size_t)(n0 + r) * Cdim + u * 16) =
            *reinterpret_cast<const uint4*>(&tile[r][u * 16]);
      }

      // per-channel column partial (dequantized = what the MFMA consumes)
      float csum = 0.f;
#pragma unroll
      for (int r = 0; r < 32; ++r)
        csum += __builtin_amdgcn_cvt_f32_fp8((int)tile[r][t], 0);
      bpart[((size_t)isx * 256 + tix) * 256 + t] = csum;
      __syncthreads();  // protect ssp/tile reuse on next role
    }
  }

  cg::this_grid().sync();  // all rgbq/xq/bpart/sumexp-init visible grid-wide

  // ================= phase 2: r9-verbatim fp8 gemm =================
  unsigned char (*sB)[16384] =
      reinterpret_cast<unsigned char(*)[16384]>(smem);       // 2x16 KB
  float* part4  = reinterpret_cast<float*>(smem + 32768);
  float* part4b = reinterpret_cast<float*>(smem + 32784);
  unsigned int* is_lastp = reinterpret_cast<unsigned int*>(smem + 32800);

  const int lane = t & 63;
  const int w    = t >> 6;      // wave 0..3 -> rows w*32..+32
  const int quad = lane >> 4;
  const int l15  = lane & 15;

  // staging lane constants (r9 swizzle, proven)
  const int u_  = l15;
  const int c4  = quad;
  const int gx  = (u_ & 7) ^ ((u_ >> 3) << 2);
  const int godd = u_ >> 3;
  // reader lane constants
  const int sxor = (l15 & 7) ^ ((quad >> 1) << 2);
  const int boff = ((quad >> 1) << 7) + ((quad & 1) << 3);

  for (int tileId = blockIdx.x; tileId < 1024; tileId += gridDim.x) {
    const int strip = tileId & 15;  // XCD-pinned: tileId%8 == blockIdx.x%8
    const int rg = tileId >> 4;

    // ---- A fragments first (r9 order) ----
    long areg[8][2];
#pragma unroll
    for (int mi = 0; mi < 2; ++mi) {
      const unsigned char* rp =
          rgbq + (size_t)(rg * 128 + w * 32 + mi * 16 + l15) * Cdim + quad * 8;
#pragma unroll
      for (int s = 0; s < 8; ++s)
        areg[s][mi] = *reinterpret_cast<const long*>(rp + s * 32);
    }

    float rowexp[8];
#pragma unroll
    for (int i = 0; i < 8; ++i) rowexp[i] = 0.f;

    const unsigned char* Bbase = xq + (size_t)strip * 512 * Cdim;

    // prefetch chunk 0 into buf 0 (after A loads: r9 order)
#pragma unroll
    for (int i = 0; i < 4; ++i) {
      const int colw = w * 16 + i * 4 + c4;
      const unsigned char* gp = Bbase + (size_t)colw * Cdim +
                                32 * (gx ^ (colw & 7)) + godd * 16;
      unsigned char* lp = &sB[0][(w * 16 + i * 4) * 256];
      __builtin_amdgcn_global_load_lds(
          (const __attribute__((address_space(1))) void*)gp,
          (__attribute__((address_space(3))) void*)lp, 16, 0, 0);
    }
    __syncthreads();

    for (int c = 0; c < 8; ++c) {
      const int bf = c & 1;
      if (c < 7) {  // prefetch next chunk (overlaps this chunk's MFMA)
#pragma unroll
        for (int i = 0; i < 4; ++i) {
          const int colw = w * 16 + i * 4 + c4;
          const unsigned char* gp =
              Bbase + (size_t)((c + 1) * 64 + colw) * Cdim +
              32 * (gx ^ (colw & 7)) + godd * 16;
          unsigned char* lp = &sB[bf ^ 1][(w * 16 + i * 4) * 256];
          __builtin_amdgcn_global_load_lds(
              (const __attribute__((address_space(1))) void*)gp,
              (__attribute__((address_space(3))) void*)lp, 16, 0, 0);
        }
      }

      f32x4 acc[2][4];
#pragma unroll
      for (int mi = 0; mi < 2; ++mi)
#pragma unroll
        for (int ni = 0; ni < 4; ++ni)
          acc[mi][ni] = (f32x4){0.f, 0.f, 0.f, 0.f};

#pragma unroll
      for (int s = 0; s < 8; ++s) {
        const int soff = ((s ^ sxor) << 4) + boff;
        long bfr[4];
#pragma unroll
        for (int ni = 0; ni < 4; ++ni)
          bfr[ni] = *reinterpret_cast<const long*>(
              &sB[bf][(ni * 16 + l15) * 256 + soff]);
#pragma unroll
        for (int mi = 0; mi < 2; ++mi)
#pragma unroll
          for (int ni = 0; ni < 4; ++ni)
            acc[mi][ni] = __builtin_amdgcn_mfma_f32_16x16x32_fp8_fp8(
                areg[s][mi], bfr[ni], acc[mi][ni], 0, 0, 0);
      }

      // rowexp += exp2(S_mfma)  (k2 pre-folded into A)
#pragma unroll
      for (int mi = 0; mi < 2; ++mi)
#pragma unroll
        for (int ni = 0; ni < 4; ++ni)
#pragma unroll
          for (int r = 0; r < 4; ++r)
            rowexp[mi * 4 + r] += __builtin_amdgcn_exp2f(acc[mi][ni][r]);

      __syncthreads();  // buffer reuse; prefetch had full compute to land
    }

    // ---- epilogue: one reduce + atomic per row slot ----
#pragma unroll
    for (int idx = 0; idx < 8; ++idx) {
      float se = rowexp[idx];
      se += __shfl_xor(se, 1);
      se += __shfl_xor(se, 2);
      se += __shfl_xor(se, 4);
      se += __shfl_xor(se, 8);
      if (l15 == 0) {
        const int row =
            rg * 128 + w * 32 + (idx >> 2) * 16 + quad * 4 + (idx & 3);
        atomicAdd(&sumexp[row], se);
      }
    }
  }

  // ================= finalize: last block computes the loss =================
  __threadfence();
  if (t == 0)
    is_lastp[0] = (atomicAdd(done, 1u) == gridDim.x - 1) ? 1u : 0u;
  __syncthreads();
  if (is_lastp[0]) {
    __threadfence();  // acquire: all blocks' sumexp atomics visible
    float lsum = 0.f;
    for (int i = t; i < Nvec; i += 256) lsum += logf(sumexp[i]);
    // analytic P: per-channel batch sums from bpart partials, then dot
    float pp = 0.f;
#pragma unroll
    for (int b = 0; b < 8; ++b) {
      float sa = 0.f, sx = 0.f;
#pragma unroll 8
      for (int s = 0; s < 32; ++s) {
        sa += bpart[(size_t)(b * 32 + s) * 256 + t];
        sx += bpart[(size_t)(256 + b * 32 + s) * 256 + t];
      }
      pp += sa * sx;
    }
#pragma unroll
    for (int off = 1; off < 64; off <<= 1) {
      lsum += __shfl_xor(lsum, off);
      pp   += __shfl_xor(pp, off);
    }
    if ((t & 63) == 0) { part4[t >> 6] = lsum; part4b[t >> 6] = pp; }
    __syncthreads();
    if (t == 0) {
      float total_lse = 0.f, P = 0.f;
#pragma unroll
      for (int i = 0; i < 4; ++i) { total_lse += part4[i]; P += part4b[i]; }
      P *= 0.69314718056f;  // ln 2
      out[0] = -(P - 1024.0f * total_lse) / (8388608.0f + 1e-8f);
    }
  }
}

extern "C" void kernel_launch(void* const* d_in, const int* in_sizes, int n_in,
                              void* d_out, int out_size, void* d_ws,
                              size_t ws_size, hipStream_t stream) {
  const float* rgb = (const float*)d_in[0];
  const float* x   = (const float*)d_in[1];
  char* ws = (char*)d_ws;
  unsigned char* rgbq = (unsigned char*)ws;                             // 2 MiB
  unsigned char* xq   = (unsigned char*)(ws + (size_t)2 * 1024 * 1024); // 2 MiB
  float* sumexp = (float*)(ws + (size_t)4 * 1024 * 1024);  // 8192 floats
  float* bpart  = sumexp + Nvec;                           // 2*256*256 floats
  unsigned int* done = (unsigned int*)(bpart + 2 * 256 * 256);
  float* outp = (float*)d_out;

  int maxB = 0;
  hipOccupancyMaxActiveBlocksPerMultiprocessor(&maxB, fused_kernel, 256, 0);
  if (maxB < 1) maxB = 2;          // conservative fallback
  int grid = maxB * 256;           // 256 CUs on MI355X
  if (grid > 1024) grid = 1024;    // no more than the tile count

  void* args[] = {(void*)&rgb, (void*)&x, (void*)&rgbq, (void*)&xq,
                  (void*)&bpart, (void*)&sumexp, (void*)&done, (void*)&outp};
  hipLaunchCooperativeKernel(fused_kernel, dim3(grid), dim3(256), args, 0,
                             stream);
}

// Round 14
// 125.397 us; speedup vs baseline: 1.8121x; 1.8121x over previous
//
#include <hip/hip_runtime.h>
#include <hip/hip_bf16.h>

// CrossModalContrastiveLoss: B=8, C=256, H=W=32 -> N=8192 vectors of dim 256.
// loss = -( P - 1024 * sum_i log(sum_j exp(S_ij)) ) / 8388608,
// S = normalize(rgb) @ normalize(x)^T / 0.1.
// P analytic via bilinearity (verified r7-r13): P = ln2 * sum_b <rgbsum_b, xsum_b>
// (rgb side carries k2 = 10*log2(e) folded in at fp8 quantization, so
// S_mfma = k2*sim and exp(10 sim) = exp2(S_mfma)).
//
// Round-14 = the two proven bests, combined for the first time:
//  * norm: r12's (float4 loads, init folded in, bpart partial stores,
//    natural (N,C) fp8 output, 2 dispatches total) -> 54-us residual.
//  * gemm: r9-VERBATIM 53-us config -- prologue order A-loads -> constants ->
//    rowexp -> prefetch -> barrier (r12's reorder alone cost +18 us; this
//    structure is schedule-fragile, do not touch), b64 LDS reads with the
//    pair-preserving swizzle (4.2e6 conflicts = structural floor, cheaper
//    than every alternative tried: r8 direct-B, r10/r11 b128 all spilled).
// Cooperative fusion (r13) regressed 2x: ROCm grid.sync with 1024 blocks
// costs ~150 us. Abandoned.

#define HWsz 1024
#define Cdim 256
#define Nvec 8192
#define CHW  (Cdim * HWsz)
#define NBLK 1024   // 16 strips x 64 rowgroups

typedef __attribute__((ext_vector_type(4))) float f32x4;

// Block = 32 vectors (one batch), 256 threads: part = t>>3 (channel chunk of
// 8), q = t&7 (vector quad). float4 loads: lane reads 16 B contiguous.
__global__ __launch_bounds__(256) void norm_kernel(
    const float* __restrict__ rgb, const float* __restrict__ x,
    unsigned char* __restrict__ rgbq, unsigned char* __restrict__ xq,
    float* __restrict__ bpart, float* __restrict__ sumexp,
    unsigned int* __restrict__ done) {
  __shared__ float ssp[32][33];
  __shared__ __align__(16) unsigned char tile[32][272];  // 272 = 16*17
  const int t = threadIdx.x;
  const int part = t >> 3;      // channel chunk (8 channels)
  const int q = t & 7;          // vector quad (4 vectors)
  const int isx = blockIdx.y;
  const float* src = isx ? x : rgb;
  unsigned char* dst = isx ? xq : rgbq;
  const int n0 = blockIdx.x * 32;
  const int b = n0 >> 10;       // batch, uniform per block
  const int hw0 = n0 & 1023;
  const float* p =
      src + (size_t)b * CHW + (size_t)part * 8 * HWsz + hw0 + q * 4;

  // init gemm-side buffers (safe: gemm is stream-ordered after this kernel)
  if (isx == 0) {
    if (t < 32) sumexp[blockIdx.x * 32 + t] = 0.f;
    if (blockIdx.x == 0 && t == 0) done[0] = 0u;
  }

  // va[k][j]: vector q*4+k, channel part*8+j
  float va[4][8];
  float ss[4] = {0.f, 0.f, 0.f, 0.f};
#pragma unroll
  for (int j = 0; j < 8; ++j) {
    const float4 v4 = *reinterpret_cast<const float4*>(p + (size_t)j * HWsz);
    va[0][j] = v4.x; va[1][j] = v4.y; va[2][j] = v4.z; va[3][j] = v4.w;
    ss[0] += v4.x * v4.x; ss[1] += v4.y * v4.y;
    ss[2] += v4.z * v4.z; ss[3] += v4.w * v4.w;
  }
#pragma unroll
  for (int k = 0; k < 4; ++k) ssp[part][q * 4 + k] = ss[k];
  __syncthreads();

  const float k2 = 14.4269504089f;  // (1/T) * log2(e), folded into rgb side
  const float topf = isx ? 1.0f : k2;
#pragma unroll
  for (int k = 0; k < 4; ++k) {
    float tot = 0.f;
#pragma unroll
    for (int p2 = 0; p2 < 32; ++p2) tot += ssp[p2][q * 4 + k];
    const float inv = topf / fmaxf(sqrtf(tot), 1e-12f);
    int pk0 = 0, pk1 = 0;
    pk0 = __builtin_amdgcn_cvt_pk_fp8_f32(va[0][0] * inv, va[0][1] * inv, pk0, false);
    pk0 = __builtin_amdgcn_cvt_pk_fp8_f32(va[0][2] * inv, va[0][3] * inv, pk0, true);
    pk1 = __builtin_amdgcn_cvt_pk_fp8_f32(va[0][4] * inv, va[0][5] * inv, pk1, false);
    pk1 = __builtin_amdgcn_cvt_pk_fp8_f32(va[0][6] * inv, va[0][7] * inv, pk1, true);
    // shift va rows down so va[0] is always the active k (keeps indices const)
#pragma unroll
    for (int kk = 0; kk < 3; ++kk)
#pragma unroll
      for (int j = 0; j < 8; ++j) va[kk][j] = va[kk + 1][j];
    unsigned int* wp =
        reinterpret_cast<unsigned int*>(&tile[q * 4 + k][part * 8]);
    wp[0] = (unsigned int)pk0;
    wp[1] = (unsigned int)pk1;
  }
  __syncthreads();

  // coalesced store: 2 passes x (16 rows x 256 B), natural (N,C) layout
#pragma unroll
  for (int pass = 0; pass < 2; ++pass) {
    const int r = pass * 16 + (t >> 4);
    const int u = t & 15;
    *reinterpret_cast<uint4*>(dst + (size_t)(n0 + r) * Cdim + u * 16) =
        *reinterpret_cast<const uint4*>(&tile[r][u * 16]);
  }

  // per-channel column partial over this block's 32 vectors (dequantized =
  // exactly what the MFMA consumes). Plain store -> no init needed.
  float csum = 0.f;
#pragma unroll
  for (int r = 0; r < 32; ++r)
    csum += __builtin_amdgcn_cvt_f32_fp8((int)tile[r][t], 0);
  bpart[((size_t)isx * 256 + blockIdx.x) * 256 + t] = csum;
}

// Block = 4 waves, 128 rows x 512-col strip, fp8 (r9-verbatim). A-panel 32
// regs/wave. B: 8 chunks of 64 cols through double-buffered 2x16 KB LDS.
// fp8 LDS swizzle (16-B staging granule): col's 16 units placed at
//   phys(unit) = ((unit>>1) ^ (col&7) ^ ((unit&1)<<2)) + ((unit&1)<<3),
// inverted on the global address side to respect global_load_lds's
// wave-uniform-base + lane*16 constraint. b64 reads. 4 blocks/CU.
__global__ __launch_bounds__(256, 4) void gemm_loss_kernel(
    const unsigned char* __restrict__ A, const unsigned char* __restrict__ Bq,
    float* __restrict__ sumexp, const float* __restrict__ bpart,
    unsigned int* __restrict__ done, float* __restrict__ out) {
  __shared__ __align__(16) unsigned char sB[2][16384];
  __shared__ float part4[4], part4b[4];
  __shared__ unsigned int is_last;

  const int tid  = threadIdx.x;
  const int lane = tid & 63;
  const int w    = tid >> 6;      // wave 0..3 -> rows w*32..+32
  const int strip = blockIdx.x;   // 0..15: cols strip*512..+512 (XCD-pinned)
  const int rg   = blockIdx.y;    // 0..63: rows rg*128..+128
  const int quad = lane >> 4;
  const int l15  = lane & 15;

  // ---- A fragments: direct global -> 32 regs/wave, once per block ----
  long areg[8][2];
#pragma unroll
  for (int mi = 0; mi < 2; ++mi) {
    const unsigned char* rp =
        A + (size_t)(rg * 128 + w * 32 + mi * 16 + l15) * Cdim + quad * 8;
#pragma unroll
    for (int s = 0; s < 8; ++s)
      areg[s][mi] = *reinterpret_cast<const long*>(rp + s * 32);
  }

  // staging lane constants: lane = c4*16 + u writes (col base+c4, slot u)
  const int u_  = l15;
  const int c4  = quad;
  const int gx  = (u_ & 7) ^ ((u_ >> 3) << 2);
  const int godd = u_ >> 3;   // global unit parity this slot holds
  // reader lane constants
  const int sxor = (l15 & 7) ^ ((quad >> 1) << 2);
  const int boff = ((quad >> 1) << 7) + ((quad & 1) << 3);

  float rowexp[8];
#pragma unroll
  for (int i = 0; i < 8; ++i) rowexp[i] = 0.f;

  const unsigned char* Bbase = Bq + (size_t)strip * 512 * Cdim;

  // prefetch chunk 0
#pragma unroll
  for (int i = 0; i < 4; ++i) {
    const int colw = w * 16 + i * 4 + c4;
    const unsigned char* gp = Bbase + (size_t)colw * Cdim +
                              32 * (gx ^ (colw & 7)) + godd * 16;
    unsigned char* lp = &sB[0][(w * 16 + i * 4) * 256];
    __builtin_amdgcn_global_load_lds(
        (const __attribute__((address_space(1))) void*)gp,
        (__attribute__((address_space(3))) void*)lp, 16, 0, 0);
  }
  __syncthreads();

  for (int c = 0; c < 8; ++c) {
    const int bf = c & 1;
    if (c < 7) {  // prefetch next chunk (overlaps this chunk's MFMA)
#pragma unroll
      for (int i = 0; i < 4; ++i) {
        const int colw = w * 16 + i * 4 + c4;
        const unsigned char* gp = Bbase + (size_t)((c + 1) * 64 + colw) * Cdim +
                                  32 * (gx ^ (colw & 7)) + godd * 16;
        unsigned char* lp = &sB[bf ^ 1][(w * 16 + i * 4) * 256];
        __builtin_amdgcn_global_load_lds(
            (const __attribute__((address_space(1))) void*)gp,
            (__attribute__((address_space(3))) void*)lp, 16, 0, 0);
      }
    }

    f32x4 acc[2][4];
#pragma unroll
    for (int mi = 0; mi < 2; ++mi)
#pragma unroll
      for (int ni = 0; ni < 4; ++ni) acc[mi][ni] = (f32x4){0.f, 0.f, 0.f, 0.f};

#pragma unroll
    for (int s = 0; s < 8; ++s) {
      const int soff = ((s ^ sxor) << 4) + boff;
      long bfr[4];
#pragma unroll
      for (int ni = 0; ni < 4; ++ni)
        bfr[ni] = *reinterpret_cast<const long*>(
            &sB[bf][(ni * 16 + l15) * 256 + soff]);
#pragma unroll
      for (int mi = 0; mi < 2; ++mi)
#pragma unroll
        for (int ni = 0; ni < 4; ++ni)
          acc[mi][ni] = __builtin_amdgcn_mfma_f32_16x16x32_fp8_fp8(
              areg[s][mi], bfr[ni], acc[mi][ni], 0, 0, 0);
    }

    // rowexp += exp2(S_mfma)  (k2 pre-folded into A)
#pragma unroll
    for (int mi = 0; mi < 2; ++mi)
#pragma unroll
      for (int ni = 0; ni < 4; ++ni)
#pragma unroll
        for (int r = 0; r < 4; ++r)
          rowexp[mi * 4 + r] += __builtin_amdgcn_exp2f(acc[mi][ni][r]);

    __syncthreads();  // buffer reuse; prefetch had full compute to land
  }

  // ---- epilogue: one reduce + atomic per row slot ----
#pragma unroll
  for (int idx = 0; idx < 8; ++idx) {
    float se = rowexp[idx];
    se += __shfl_xor(se, 1);
    se += __shfl_xor(se, 2);
    se += __shfl_xor(se, 4);
    se += __shfl_xor(se, 8);
    if (l15 == 0) {
      const int row =
          rg * 128 + w * 32 + (idx >> 2) * 16 + quad * 4 + (idx & 3);
      atomicAdd(&sumexp[row], se);
    }
  }

  // ---- last block finalizes the loss ----
  if (tid == 0) {
    __threadfence();
    is_last = (atomicAdd(done, 1u) == NBLK - 1) ? 1u : 0u;
  }
  __syncthreads();
  if (is_last) {
    __threadfence();  // acquire: all blocks' sumexp atomics visible
    float lsum = 0.f;
    for (int i = tid; i < Nvec; i += 256) lsum += logf(sumexp[i]);
    // analytic P: per-channel batch sums from bpart partials, then dot
    float pp = 0.f;
#pragma unroll
    for (int b = 0; b < 8; ++b) {
      float sa = 0.f, sx = 0.f;
#pragma unroll 8
      for (int s = 0; s < 32; ++s) {
        sa += bpart[(size_t)(b * 32 + s) * 256 + tid];
        sx += bpart[(size_t)(256 + b * 32 + s) * 256 + tid];
      }
      pp += sa * sx;
    }
#pragma unroll
    for (int off = 1; off < 64; off <<= 1) {
      lsum += __shfl_xor(lsum, off);
      pp   += __shfl_xor(pp, off);
    }
    if ((tid & 63) == 0) { part4[tid >> 6] = lsum; part4b[tid >> 6] = pp; }
    __syncthreads();
    if (tid == 0) {
      float total_lse = 0.f, P = 0.f;
#pragma unroll
      for (int i = 0; i < 4; ++i) { total_lse += part4[i]; P += part4b[i]; }
      P *= 0.69314718056f;  // ln 2
      out[0] = -(P - 1024.0f * total_lse) / (8388608.0f + 1e-8f);
    }
  }
}

extern "C" void kernel_launch(void* const* d_in, const int* in_sizes, int n_in,
                              void* d_out, int out_size, void* d_ws,
                              size_t ws_size, hipStream_t stream) {
  const float* rgb = (const float*)d_in[0];
  const float* x   = (const float*)d_in[1];
  char* ws = (char*)d_ws;
  unsigned char* rgbq = (unsigned char*)ws;                             // 2 MiB
  unsigned char* xq   = (unsigned char*)(ws + (size_t)2 * 1024 * 1024); // 2 MiB
  float* sumexp = (float*)(ws + (size_t)4 * 1024 * 1024);  // 8192 floats
  float* bpart  = sumexp + Nvec;                           // 2*256*256 floats
  unsigned int* done = (unsigned int*)(bpart + 2 * 256 * 256);

  norm_kernel<<<dim3(256, 2), 256, 0, stream>>>(rgb, x, rgbq, xq, bpart,
                                                sumexp, done);
  gemm_loss_kernel<<<dim3(16, 64), 256, 0, stream>>>(rgbq, xq, sumexp, bpart,
                                                     done, (float*)d_out);
}